// Round 1
// baseline (815.261 us; speedup 1.0000x reference)
//
#include <hip/hip_runtime.h>
#include <cstddef>

#define LSEQ 4096

__device__ __forceinline__ float dot4(float4 a, float4 w, float acc) {
  return fmaf(a.x, w.x, fmaf(a.y, w.y, fmaf(a.z, w.z, fmaf(a.w, w.w, acc))));
}
__device__ __forceinline__ float sigm_(float v) { return 1.0f / (1.0f + __expf(-v)); }
__device__ __forceinline__ float silu_(float v) { return v / (1.0f + __expf(-v)); }
__device__ __forceinline__ float softplus_(float v) {
  return fmaxf(v, 0.0f) + log1pf(__expf(-fabsf(v)));
}

// K1: 1x1 conv in (x[b,c,h,w] @ W_in^T + b_in) + LayerNorm -> tok[b, L, 64]
__global__ __launch_bounds__(256) void k_inproj_ln(
    const float* __restrict__ x, const float* __restrict__ W_in,
    const float* __restrict__ b_in, const float* __restrict__ ln_g,
    const float* __restrict__ ln_b, float* __restrict__ tok)
{
  __shared__ float xl[64][68];
  __shared__ float red[8][65];
  __shared__ float mu_s[64], rs_s[64];
  const int b = blockIdx.x >> 6, row = blockIdx.x & 63;
  const int p0 = row << 6;
  const int tid = threadIdx.x;
  const int t = tid & 63;
  const int g = tid >> 6;
  const int gu = __builtin_amdgcn_readfirstlane(g);
  for (int c = gu; c < 64; c += 4)
    xl[t][c] = x[((size_t)(b * 64 + c) << 12) + p0 + t];
  __syncthreads();
  float acc[16];
#pragma unroll
  for (int i = 0; i < 16; ++i) acc[i] = b_in[gu * 16 + i];
  for (int c4 = 0; c4 < 16; ++c4) {
    const float4 a = *(const float4*)&xl[t][c4 * 4];
#pragma unroll
    for (int i = 0; i < 16; ++i) {
      const float4 w = *(const float4*)&W_in[(gu * 16 + i) * 64 + c4 * 4];
      acc[i] = dot4(a, w, acc[i]);
    }
  }
  float s1 = 0.f, s2 = 0.f;
#pragma unroll
  for (int i = 0; i < 16; ++i) { s1 += acc[i]; s2 += acc[i] * acc[i]; }
  red[gu * 2][t] = s1; red[gu * 2 + 1][t] = s2;
  __syncthreads();
  if (g == 0) {
    const float S1 = red[0][t] + red[2][t] + red[4][t] + red[6][t];
    const float S2 = red[1][t] + red[3][t] + red[5][t] + red[7][t];
    const float mu = S1 * (1.0f / 64.0f);
    const float var = S2 * (1.0f / 64.0f) - mu * mu;
    mu_s[t] = mu; rs_s[t] = rsqrtf(var + 1e-5f);
  }
  __syncthreads();
  const float mu = mu_s[t], rs = rs_s[t];
  float o[16];
#pragma unroll
  for (int i = 0; i < 16; ++i) {
    const int d = gu * 16 + i;
    o[i] = (acc[i] - mu) * rs * ln_g[d] + ln_b[d];
  }
  float4* dst = (float4*)&tok[(((size_t)b * LSEQ) + p0 + t) * 64 + gu * 16];
#pragma unroll
  for (int i = 0; i < 4; ++i)
    dst[i] = make_float4(o[4 * i], o[4 * i + 1], o[4 * i + 2], o[4 * i + 3]);
}

// K2: fused mamba in_proj (xr half) -> causal depthwise conv -> silu -> x_proj -> dt_proj
// Stores xs, delta, BC in LOGICAL (scan) order for the given direction.
__global__ __launch_bounds__(256) void k_stage1(
    const float* __restrict__ tok, const float* __restrict__ W_mi,
    const float* __restrict__ conv_w, const float* __restrict__ conv_b,
    const float* __restrict__ W_xp, const float* __restrict__ W_dt,
    const float* __restrict__ b_dt, float* __restrict__ xs,
    float* __restrict__ dlt, float* __restrict__ BC, const int dir)
{
  __shared__ float tokl[67][68];   // row j <-> logical q = p0-3+j
  __shared__ float xrl[67][132];   // xr rows; rows 0..63 reused for xs
  __shared__ float xdl[64][40];
  const int b = blockIdx.x >> 6, tile = blockIdx.x & 63;
  const int p0 = tile << 6;
  const int tid = threadIdx.x;
  const int t = tid & 63;
  const int g = tid >> 6;
  const int gu = __builtin_amdgcn_readfirstlane(g);

  for (int j = gu; j < 67; j += 4) {
    const int q = p0 - 3 + j;
    float v = 0.f;
    if (q >= 0) {
      const int ph = dir ? (LSEQ - 1 - q) : q;
      v = tok[((size_t)b * LSEQ + ph) * 64 + t];
    }
    tokl[j][t] = v;
  }
  __syncthreads();

  // xr = tok @ W_mi[0:128]^T for rows t (and halo rows 64+t for t<3)
  for (int pass = 0; pass < 2; ++pass) {
    if (pass && t >= 3) break;
    const int r = pass ? (64 + t) : t;
#pragma unroll
    for (int fb = 0; fb < 4; ++fb) {
      float a8[8];
#pragma unroll
      for (int i = 0; i < 8; ++i) a8[i] = 0.f;
      for (int c4 = 0; c4 < 16; ++c4) {
        const float4 a = *(const float4*)&tokl[r][c4 * 4];
#pragma unroll
        for (int i = 0; i < 8; ++i) {
          const float4 w = *(const float4*)&W_mi[(gu * 32 + fb * 8 + i) * 64 + c4 * 4];
          a8[i] = dot4(a, w, a8[i]);
        }
      }
#pragma unroll
      for (int i2 = 0; i2 < 2; ++i2)
        *(float4*)&xrl[r][gu * 32 + fb * 8 + i2 * 4] =
            make_float4(a8[i2 * 4], a8[i2 * 4 + 1], a8[i2 * 4 + 2], a8[i2 * 4 + 3]);
    }
  }
  __syncthreads();

  // causal depthwise conv (d_conv=4) + silu, token p0+t reads xr rows t..t+3
  float xsv[32];
#pragma unroll
  for (int i4 = 0; i4 < 8; ++i4) {
    const int d0 = gu * 32 + i4 * 4;
    float4 a = *(const float4*)&conv_b[d0];
#pragma unroll
    for (int k = 0; k < 4; ++k) {
      const float4 xv = *(const float4*)&xrl[t + k][d0];
      a.x = fmaf(conv_w[(d0 + 0) * 4 + k], xv.x, a.x);
      a.y = fmaf(conv_w[(d0 + 1) * 4 + k], xv.y, a.y);
      a.z = fmaf(conv_w[(d0 + 2) * 4 + k], xv.z, a.z);
      a.w = fmaf(conv_w[(d0 + 3) * 4 + k], xv.w, a.w);
    }
    xsv[i4 * 4 + 0] = silu_(a.x);
    xsv[i4 * 4 + 1] = silu_(a.y);
    xsv[i4 * 4 + 2] = silu_(a.z);
    xsv[i4 * 4 + 3] = silu_(a.w);
  }
  __syncthreads();
  {
    float* gxs = &xs[(((size_t)b * LSEQ) + p0 + t) * 128 + gu * 32];
#pragma unroll
    for (int i4 = 0; i4 < 8; ++i4) {
      const float4 v = make_float4(xsv[i4 * 4], xsv[i4 * 4 + 1], xsv[i4 * 4 + 2], xsv[i4 * 4 + 3]);
      *(float4*)&xrl[t][gu * 32 + i4 * 4] = v;   // reuse rows 0..63 as xs tile
      *(float4*)&gxs[i4 * 4] = v;
    }
  }
  __syncthreads();

  // xdbl = xs @ W_xp^T  (36 outputs; e = gu*9 + j)
  {
    float acc9[9];
#pragma unroll
    for (int j = 0; j < 9; ++j) acc9[j] = 0.f;
    for (int c4 = 0; c4 < 32; ++c4) {
      const float4 a = *(const float4*)&xrl[t][c4 * 4];
#pragma unroll
      for (int j = 0; j < 9; ++j) {
        const float4 w = *(const float4*)&W_xp[(gu * 9 + j) * 128 + c4 * 4];
        acc9[j] = dot4(a, w, acc9[j]);
      }
    }
#pragma unroll
    for (int j = 0; j < 9; ++j) xdl[t][gu * 9 + j] = acc9[j];
  }
  __syncthreads();

  // delta = softplus(dt @ W_dt^T + b_dt); BC out
  {
    const float r0 = xdl[t][0], r1 = xdl[t][1], r2 = xdl[t][2], r3 = xdl[t][3];
    float* gdl = &dlt[(((size_t)b * LSEQ) + p0 + t) * 128 + gu * 32];
#pragma unroll
    for (int i4 = 0; i4 < 8; ++i4) {
      float tmp[4];
#pragma unroll
      for (int ii = 0; ii < 4; ++ii) {
        const int d = gu * 32 + i4 * 4 + ii;
        const float4 w = *(const float4*)&W_dt[d * 4];
        tmp[ii] = softplus_(b_dt[d] + r0 * w.x + r1 * w.y + r2 * w.z + r3 * w.w);
      }
      *(float4*)&gdl[i4 * 4] = make_float4(tmp[0], tmp[1], tmp[2], tmp[3]);
    }
    float* gbc = &BC[(((size_t)b * LSEQ) + p0 + t) * 32 + gu * 8];
#pragma unroll
    for (int jj = 0; jj < 8; ++jj) gbc[jj] = xdl[t][4 + gu * 8 + jj];
  }
}

// K3: scan pass 1 — per (b, chunk of 64): local scan from 0, emit chunk transition
__global__ __launch_bounds__(128) void k_scan1(
    const float* __restrict__ dlt, const float* __restrict__ xs,
    const float* __restrict__ BC, const float* __restrict__ A_log,
    float* __restrict__ chA, float* __restrict__ chB)
{
  __shared__ float bcs[16][33];
  const int b = blockIdx.x >> 6, c = blockIdx.x & 63;
  const int d = threadIdx.x;
  float A[16];
#pragma unroll
  for (int n = 0; n < 16; ++n) A[n] = -__expf(A_log[d * 16 + n]);
  float s[16];
#pragma unroll
  for (int n = 0; n < 16; ++n) s[n] = 0.f;
  float sd = 0.f;
  const size_t base = (size_t)b * LSEQ + c * 64;
  for (int seg = 0; seg < 4; ++seg) {
    __syncthreads();
    for (int i = threadIdx.x; i < 512; i += 128) {
      const int st = i >> 5, j = i & 31;
      bcs[st][j] = BC[(base + seg * 16 + st) * 32 + j];
    }
    float dlr[16], ur[16];
#pragma unroll
    for (int st = 0; st < 16; ++st) {
      const size_t p = (base + seg * 16 + st) * 128 + d;
      dlr[st] = dlt[p];
      ur[st] = xs[p];
    }
    __syncthreads();
#pragma unroll
    for (int st = 0; st < 16; ++st) {
      const float dl = dlr[st];
      const float du = dl * ur[st];
      sd += dl;
#pragma unroll
      for (int n = 0; n < 16; ++n)
        s[n] = fmaf(__expf(A[n] * dl), s[n], du * bcs[st][n]);
    }
  }
  float* oA = &chA[((size_t)blockIdx.x * 128 + d) * 16];
  float* oB = &chB[((size_t)blockIdx.x * 128 + d) * 16];
#pragma unroll
  for (int n = 0; n < 16; ++n) { oA[n] = __expf(A[n] * sd); oB[n] = s[n]; }
}

// K4: combine chunk transitions sequentially; chB becomes the per-chunk INITIAL state in place
__global__ __launch_bounds__(256) void k_scanfix(const float* __restrict__ chA, float* chB)
{
  const int idx = blockIdx.x * 256 + threadIdx.x;   // 16*128*16 = 32768
  const int b = idx >> 11, lo = idx & 2047;
  float s = 0.f;
  for (int c = 0; c < 64; ++c) {
    const size_t a = ((size_t)(b * 64 + c) << 11) + lo;
    const float sOld = s;
    s = fmaf(chA[a], s, chB[a]);
    chB[a] = sOld;
  }
}

// K5: scan pass 2 — replay with correct init, emit y (+ u*D) in-place over delta buffer
__global__ __launch_bounds__(128) void k_scan2(
    float* dlt, const float* __restrict__ xs,
    const float* __restrict__ BC, const float* __restrict__ A_log,
    const float* __restrict__ Dp, const float* __restrict__ sIn)
{
  __shared__ float bcs[16][33];
  const int b = blockIdx.x >> 6, c = blockIdx.x & 63;
  const int d = threadIdx.x;
  float A[16];
#pragma unroll
  for (int n = 0; n < 16; ++n) A[n] = -__expf(A_log[d * 16 + n]);
  float s[16];
  const float* si = &sIn[((size_t)blockIdx.x * 128 + d) * 16];
#pragma unroll
  for (int n = 0; n < 16; ++n) s[n] = si[n];
  const float Dv = Dp[d];
  const size_t base = (size_t)b * LSEQ + c * 64;
  for (int seg = 0; seg < 4; ++seg) {
    __syncthreads();
    for (int i = threadIdx.x; i < 512; i += 128) {
      const int st = i >> 5, j = i & 31;
      bcs[st][j] = BC[(base + seg * 16 + st) * 32 + j];
    }
    float dlr[16], ur[16];
#pragma unroll
    for (int st = 0; st < 16; ++st) {
      const size_t p = (base + seg * 16 + st) * 128 + d;
      dlr[st] = dlt[p];
      ur[st] = xs[p];
    }
    __syncthreads();
#pragma unroll
    for (int st = 0; st < 16; ++st) {
      const float dl = dlr[st];
      const float u = ur[st];
      const float du = dl * u;
      float y = 0.f;
#pragma unroll
      for (int n = 0; n < 16; ++n) {
        s[n] = fmaf(__expf(A[n] * dl), s[n], du * bcs[st][n]);
        y = fmaf(s[n], bcs[st][16 + n], y);
      }
      y = fmaf(u, Dv, y);
      dlt[(base + seg * 16 + st) * 128 + d] = y;
    }
  }
}

// K6: gate y * silu(z) (z recomputed from tok) -> @ W_mo^T -> 0.5x accumulate into ymo (physical order)
__global__ __launch_bounds__(256) void k_gate(
    const float* __restrict__ y, const float* __restrict__ tok,
    const float* __restrict__ W_mi, const float* __restrict__ W_mo,
    float* __restrict__ ymo, const int dir)
{
  __shared__ float yl[64][132];
  __shared__ float tkl[64][68];    // reused as output tile after z-phase
  const int b = blockIdx.x >> 6, tile = blockIdx.x & 63;
  const int p0 = tile << 6;
  const int tid = threadIdx.x, t = tid & 63, g = tid >> 6;
  const int gu = __builtin_amdgcn_readfirstlane(g);
  {
    const float* gy = &y[(((size_t)b * LSEQ) + p0 + t) * 128 + gu * 32];
#pragma unroll
    for (int i4 = 0; i4 < 8; ++i4)
      *(float4*)&yl[t][gu * 32 + i4 * 4] = *(const float4*)&gy[i4 * 4];
  }
  for (int j = gu; j < 64; j += 4) {
    const int q = p0 + j;
    const int ph = dir ? (LSEQ - 1 - q) : q;
    tkl[j][t] = tok[((size_t)b * LSEQ + ph) * 64 + t];
  }
  __syncthreads();
  // z = tok @ W_mi[128:256]^T ; g = y * silu(z)
#pragma unroll
  for (int fb = 0; fb < 4; ++fb) {
    float a8[8];
#pragma unroll
    for (int i = 0; i < 8; ++i) a8[i] = 0.f;
    for (int c4 = 0; c4 < 16; ++c4) {
      const float4 a = *(const float4*)&tkl[t][c4 * 4];
#pragma unroll
      for (int i = 0; i < 8; ++i) {
        const float4 w = *(const float4*)&W_mi[(128 + gu * 32 + fb * 8 + i) * 64 + c4 * 4];
        a8[i] = dot4(a, w, a8[i]);
      }
    }
#pragma unroll
    for (int i = 0; i < 8; ++i) {
      const int dd = gu * 32 + fb * 8 + i;
      yl[t][dd] = yl[t][dd] * silu_(a8[i]);
    }
  }
  __syncthreads();
  // ymo_tile = 0.5 * g @ W_mo^T  (writes into tkl, safe after barrier)
#pragma unroll
  for (int fb = 0; fb < 2; ++fb) {
    float a8[8];
#pragma unroll
    for (int i = 0; i < 8; ++i) a8[i] = 0.f;
    for (int c4 = 0; c4 < 32; ++c4) {
      const float4 a = *(const float4*)&yl[t][c4 * 4];
#pragma unroll
      for (int i = 0; i < 8; ++i) {
        const float4 w = *(const float4*)&W_mo[(gu * 16 + fb * 8 + i) * 128 + c4 * 4];
        a8[i] = dot4(a, w, a8[i]);
      }
    }
#pragma unroll
    for (int i = 0; i < 8; ++i) tkl[t][gu * 16 + fb * 8 + i] = 0.5f * a8[i];
  }
  __syncthreads();
  for (int j = gu; j < 64; j += 4) {
    const int q = p0 + j;
    const int ph = dir ? (LSEQ - 1 - q) : q;
    const size_t o = ((size_t)b * LSEQ + ph) * 64 + t;
    if (dir == 0) ymo[o] = tkl[j][t];
    else          ymo[o] += tkl[j][t];
  }
}

// K7: final 1x1 conv (ymo @ W_out^T + b_out) -> sigmoid - 0.5, to [b,c,h,w]
__global__ __launch_bounds__(256) void k_final(
    const float* __restrict__ ymo, const float* __restrict__ W_out,
    const float* __restrict__ b_out, float* __restrict__ out)
{
  __shared__ float yml[64][68];
  __shared__ float ol[64][68];
  const int b = blockIdx.x >> 6, row = blockIdx.x & 63;
  const int p0 = row << 6;
  const int tid = threadIdx.x, t = tid & 63, g = tid >> 6;
  const int gu = __builtin_amdgcn_readfirstlane(g);
  {
    const float* gy = &ymo[(((size_t)b * LSEQ) + p0 + t) * 64 + gu * 16];
#pragma unroll
    for (int i4 = 0; i4 < 4; ++i4)
      *(float4*)&yml[t][gu * 16 + i4 * 4] = *(const float4*)&gy[i4 * 4];
  }
  __syncthreads();
#pragma unroll
  for (int fb = 0; fb < 2; ++fb) {
    float a8[8];
#pragma unroll
    for (int i = 0; i < 8; ++i) a8[i] = 0.f;
    for (int c4 = 0; c4 < 16; ++c4) {
      const float4 a = *(const float4*)&yml[t][c4 * 4];
#pragma unroll
      for (int i = 0; i < 8; ++i) {
        const float4 w = *(const float4*)&W_out[(gu * 16 + fb * 8 + i) * 64 + c4 * 4];
        a8[i] = dot4(a, w, a8[i]);
      }
    }
#pragma unroll
    for (int i = 0; i < 8; ++i) {
      const int cc = gu * 16 + fb * 8 + i;
      ol[cc][t] = sigm_(a8[i] + b_out[cc]) - 0.5f;
    }
  }
  __syncthreads();
  for (int j = gu; j < 64; j += 4)
    out[((size_t)(b * 64 + j) << 12) + p0 + t] = ol[j][t];
}

extern "C" void kernel_launch(void* const* d_in, const int* in_sizes, int n_in,
                              void* d_out, int out_size, void* d_ws, size_t ws_size,
                              hipStream_t stream) {
  const float* x      = (const float*)d_in[0];
  const float* W_in   = (const float*)d_in[1];
  const float* b_in   = (const float*)d_in[2];
  const float* ln_g   = (const float*)d_in[3];
  const float* ln_b   = (const float*)d_in[4];
  const float* W_mi   = (const float*)d_in[5];
  const float* conv_w = (const float*)d_in[6];
  const float* conv_b = (const float*)d_in[7];
  const float* W_xp   = (const float*)d_in[8];
  const float* W_dt   = (const float*)d_in[9];
  const float* b_dt   = (const float*)d_in[10];
  const float* A_log  = (const float*)d_in[11];
  const float* Dp     = (const float*)d_in[12];
  const float* W_mo   = (const float*)d_in[13];
  const float* W_out  = (const float*)d_in[14];
  const float* b_out  = (const float*)d_in[15];
  float* out = (float*)d_out;

  float* ws  = (float*)d_ws;
  float* tok = ws;               // 16*4096*64      = 4,194,304
  float* xs  = tok + 4194304;    // 16*4096*128     = 8,388,608
  float* dlt = xs  + 8388608;    // 16*4096*128     = 8,388,608 (becomes y in pass2)
  float* BC  = dlt + 8388608;    // 16*4096*32      = 2,097,152
  float* chA = BC  + 2097152;    // 16*64*128*16    = 2,097,152
  float* chB = chA + 2097152;    // 2,097,152 (becomes sIn after k_scanfix)
  float* ymo = chB + 2097152;    // 16*4096*64      = 4,194,304
  // total 31,457,280 floats = 120 MiB

  k_inproj_ln<<<1024, 256, 0, stream>>>(x, W_in, b_in, ln_g, ln_b, tok);
  for (int dir = 0; dir < 2; ++dir) {
    k_stage1<<<1024, 256, 0, stream>>>(tok, W_mi, conv_w, conv_b, W_xp, W_dt, b_dt,
                                       xs, dlt, BC, dir);
    k_scan1<<<1024, 128, 0, stream>>>(dlt, xs, BC, A_log, chA, chB);
    k_scanfix<<<128, 256, 0, stream>>>(chA, chB);
    k_scan2<<<1024, 128, 0, stream>>>(dlt, xs, BC, A_log, Dp, chB);
    k_gate<<<1024, 256, 0, stream>>>(dlt, tok, W_mi, W_mo, ymo, dir);
  }
  k_final<<<1024, 256, 0, stream>>>(ymo, W_out, b_out, out);
}